// Round 18
// baseline (97.221 us; speedup 1.0000x reference)
//
#include <hip/hip_runtime.h>
#include <hip/hip_bf16.h>

#define NN 512
#define NI 64
#define NJ 16
#define DD 256
#define HI 64
#define HO 64

typedef unsigned int  u32;
typedef unsigned short u16;

typedef _Float16 f16;
typedef __attribute__((ext_vector_type(2))) _Float16 f16x2;
typedef __attribute__((ext_vector_type(8))) _Float16 f16x8;
typedef __attribute__((ext_vector_type(4))) float f32x4;

typedef __attribute__((address_space(3))) void  lds_void;
typedef const __attribute__((address_space(1))) void glob_void;

__device__ __forceinline__ float gelu_exact(float x){
    return 0.5f * x * (1.0f + erff(x * 0.7071067811865476f));
}
__device__ __forceinline__ float sigm(float x){
    return 1.0f / (1.0f + __expf(-x));
}
__device__ __forceinline__ u16 f2h(float f){
    union { f16 h; u16 u; } c; c.h = (f16)f; return c.u;
}
__device__ __forceinline__ float h2f(u16 u){
    union { u16 u; f16 h; } c; c.u = u; return (float)c.h;
}
__device__ __forceinline__ f16x2 bch2(u32 x){
    union { u32 u; f16x2 h; } c; c.u = x; return c.h;
}
__device__ __forceinline__ f16x2 habs2(f16x2 a){
    union { f16x2 h; u32 u; } c; c.h = a; c.u &= 0x7FFF7FFFu; return c.h;
}
__device__ __forceinline__ float dot2f(u32 a, u32 b, float acc){
    return __builtin_amdgcn_fdot2(bch2(a), bch2(b), acc, false);
}
__device__ __forceinline__ float dot8h(uint4 q, uint4 v, float acc){
    acc = dot2f(q.x, v.x, acc);
    acc = dot2f(q.y, v.y, acc);
    acc = dot2f(q.z, v.z, acc);
    acc = dot2f(q.w, v.w, acc);
    return acc;
}
__device__ __forceinline__ float bcast_lane(float v, int lane){
    return __uint_as_float(__builtin_amdgcn_readlane(__float_as_uint(v), lane));
}

// ---- prep: weights in gather-free layouts (16 blocks) ----
// wAf/wBf/wCtf: f32 chunk-row  out[(c*64+row)*4+e] = W[row][c*4+e] (wCt = fe1W^T)
// fn1wf: f16 MFMA A-frag order (unchanged)
__global__ __launch_bounds__(256) void k_prep_small(
    const float* __restrict__ fn1W, const float* __restrict__ fe2W,
    const float* __restrict__ fn2W, const float* __restrict__ fe1W,
    u16* __restrict__ fn1wf, float* __restrict__ wAf,
    float* __restrict__ wBf, float* __restrict__ wCtf)
{
    const int o = threadIdx.x + blockIdx.x * 256;   // 0..4095
    {
        const int c = o >> 8, row = (o >> 2) & 63, e = o & 3;
        wAf[o]  = fe2W[row * 64 + c * 4 + e];
        wBf[o]  = fn2W[row * 64 + c * 4 + e];
        wCtf[o] = fe1W[(c * 4 + e) * 64 + row];     // fe1W^T row
    }
    {
        const int q = o >> 9, ll = (o >> 3) & 63, e = o & 7;
        const int ht = q >> 1, hf = q & 1, lr = ll & 15, lg = ll >> 4;
        fn1wf[o] = f2h(fn1W[(ht * 16 + lr) * 64 + hf * 32 + lg * 8 + e]);
    }
}

// ---------------- Kernel A: xc = gelu(x @ Wcap + Bcap)  --  f16 MFMA ----------------
// XCD-bijective swizzle: the 8 same-i blocks (sharing the Wcap[i] panel) -> one XCD.
__global__ __launch_bounds__(256) void k_xc(const float* __restrict__ x,
    const float* __restrict__ Wcap, const float* __restrict__ Bcap,
    u16* __restrict__ xcb)
{
    __shared__ u16 wt_l[16384];        // 32 KB: WcapT [h][k] f16, granule-swizzled
    __shared__ u16 strip[4][1024];
    const int id = blockIdx.x;
    const int i  = ((id & 7) << 3) | (id >> 6);   // id%8 = i>>3 -> XCD
    const int nc = (id >> 3) & 7;
    const int n0 = nc * 64;
    const int t = threadIdx.x;
    const int w = t >> 6, l = t & 63;
    const int lr = l & 15, lg = l >> 4;

    {
        const float* wsrc = Wcap + (size_t)i * (DD * HI);
        const int h = t & 63, kg = t >> 6;
        #pragma unroll
        for (int p = 0; p < 32; ++p){
            const int k = (p * 4 + kg) * 2;
            u32 lo = f2h(wsrc[(size_t)k * HI + h]);
            u32 hi = f2h(wsrc[(size_t)(k + 1) * HI + h]);
            const int g = k >> 3;
            *(u32*)&wt_l[h * 256 + ((g ^ (h & 7)) << 3) + (k & 7)] = lo | (hi << 16);
        }
    }
    __syncthreads();

    const float* xrow = x + ((size_t)(n0 + 16 * w + lr) * NI + i) * DD;
    f32x4 acc[4] = {};
    #pragma unroll
    for (int ks = 0; ks < 8; ++ks){
        float4 f0 = *(const float4*)(xrow + ks * 32 + lg * 8);
        float4 f1 = *(const float4*)(xrow + ks * 32 + lg * 8 + 4);
        f16x8 a;
        a[0] = (f16)f0.x; a[1] = (f16)f0.y; a[2] = (f16)f0.z; a[3] = (f16)f0.w;
        a[4] = (f16)f1.x; a[5] = (f16)f1.y; a[6] = (f16)f1.z; a[7] = (f16)f1.w;
        #pragma unroll
        for (int ht = 0; ht < 4; ++ht){
            const int h = ht * 16 + lr;
            f16x8 b = *(const f16x8*)&wt_l[h * 256 + (((ks * 4 + lg) ^ (lr & 7)) << 3)];
            acc[ht] = __builtin_amdgcn_mfma_f32_16x16x32_f16(a, b, acc[ht], 0, 0, 0);
        }
    }

    u16* st = strip[w];
    #pragma unroll
    for (int ht = 0; ht < 4; ++ht){
        const int h = ht * 16 + lr, g = h >> 3;
        const float bc = Bcap[i * HI + h];
        #pragma unroll
        for (int r = 0; r < 4; ++r){
            const int m = lg * 4 + r;
            st[m * 64 + ((g ^ (m & 7)) << 3) + (h & 7)] = f2h(gelu_exact(acc[ht][r] + bc));
        }
    }
    {
        const int row = l >> 2, g0 = (l & 3) * 2;
        const size_t off = ((size_t)(n0 + 16 * w + row) * NI + i) * HI;
        #pragma unroll
        for (int gg = g0; gg < g0 + 2; ++gg){
            uint4 q = *(const uint4*)&st[row * 64 + ((gg ^ (row & 7)) << 3)];
            *(uint4*)(xcb + off + gg * 8) = q;
        }
    }
}

// ------- Kernel B: one block per (i,j); votes (f16 MFMA) + bij.  NO fnv. -------
__global__ __launch_bounds__(256) void k_votes(
    const u16* __restrict__ xcb, const float* __restrict__ Wv,
    const float* __restrict__ Bv, const float* __restrict__ mask,
    const float* __restrict__ scoreW, const float* __restrict__ scoreb,
    u16* __restrict__ votes, float* __restrict__ bij)
{
    __shared__ u16 vstrip[4][1024];
    const int i = blockIdx.x, j = blockIdx.y;
    const int t = threadIdx.x, w = t >> 6, l = t & 63;
    const int lr = l & 15, lg = l >> 4;
    const int isw = i & 7;

    f16x8 wb0[4], wb1[4];
    const float* wvp = Wv + (size_t)(i * NJ + j) * 4096;
    float bv[4], swv[4];
    #pragma unroll
    for (int ht = 0; ht < 4; ++ht){
        const int h = ht * 16 + lr;
        #pragma unroll
        for (int e = 0; e < 8; ++e){
            wb0[ht][e] = (f16)wvp[(lg * 8 + e) * 64 + h];
            wb1[ht][e] = (f16)wvp[(32 + lg * 8 + e) * 64 + h];
        }
        bv[ht]  = Bv[(size_t)(i * NJ + j) * HO + h];
        swv[ht] = scoreW[h];
    }
    const float sb = scoreb[0];
    u16* vst = vstrip[w];

    for (int nc = 0; nc < 8; ++nc){
        const int n0 = nc * 64 + 16 * w;
        const u16* ar = xcb + ((size_t)(n0 + lr) * NI + i) * HI + lg * 8;
        f16x8 a0 = *(const f16x8*)ar;
        f16x8 a1 = *(const f16x8*)(ar + 32);
        float mk[4];
        #pragma unroll
        for (int r = 0; r < 4; ++r)
            mk[r] = mask[(size_t)(n0 + lg * 4 + r) * NI + i];

        float p[4] = {};
        #pragma unroll
        for (int ht = 0; ht < 4; ++ht){
            f32x4 c4 = {};
            c4 = __builtin_amdgcn_mfma_f32_16x16x32_f16(a0, wb0[ht], c4, 0, 0, 0);
            c4 = __builtin_amdgcn_mfma_f32_16x16x32_f16(a1, wb1[ht], c4, 0, 0, 0);
            const int h = ht * 16 + lr, gp = h >> 3;
            #pragma unroll
            for (int r = 0; r < 4; ++r){
                const int rs = lg * 4 + r;
                float val = (c4[r] + bv[ht]) * mk[r];
                p[r] += val * swv[ht];
                vst[rs * 64 + ((gp ^ (rs & 7)) << 3) + (h & 7)] = f2h(val);
            }
        }
        #pragma unroll
        for (int r = 0; r < 4; ++r){
            float s = p[r];
            s += __shfl_xor(s, 1); s += __shfl_xor(s, 2);
            s += __shfl_xor(s, 4); s += __shfl_xor(s, 8);
            if (lr == 0)
                bij[((size_t)(n0 + lg * 4 + r) * NJ + j) * NI + i] = s + sb;
        }

        {
            const int row = l >> 2, g0 = (l & 3) * 2;
            const size_t off = (((size_t)(nc * 64 + 16 * w + row) * NJ + j) * NI + i) * HO;
            #pragma unroll
            for (int gg = g0; gg < g0 + 2; ++gg){
                uint4 qv = *(const uint4*)&vst[row * 64 + ((gg ^ (row & 7)) << 3)];
                *(uint4*)(votes + off + ((gg ^ isw) << 3)) = qv;
            }
        }
    }
}

// ---------------- Kernel C: routing; ONE wave per (n,j), ZERO barriers ----------------
// r17 body with the three UNCOVERED LDS round-trips removed:
//  - g/w and u matvecs via v_readlane broadcast of per-lane vj/g (f32 weights)
//    -> vjh and sgh mirrors deleted (no write->lgkmcnt->read stall)
//  - Mreg via predicated register (r9's `if (lg==itile)`) -> Mw array deleted
// swh/suh mirrors kept (their round-trips are covered by the u/M phases).
__global__ __launch_bounds__(256) void k_route(
    const u16* __restrict__ votes, const float* __restrict__ bijg,
    const float* __restrict__ mask,
    const float* __restrict__ alphaW, const float* __restrict__ alphab,
    const float* __restrict__ wAf, const float* __restrict__ fe2b,
    const float* __restrict__ wBf, const float* __restrict__ fn2b,
    const float* __restrict__ wCtf, const float* __restrict__ fe1b,
    const u16* __restrict__ fn1wf, const float* __restrict__ fn1b,
    const int* __restrict__ itersp, float* __restrict__ out)
{
    __shared__ u16 t_l[4][4096];                       // 8 KB votes tile per wave
    __shared__ alignas(16) u16 s_wh[4][64];            // f16 mirrors (covered trips)
    __shared__ alignas(16) u16 s_uh[4][64];

    const int t = threadIdx.x;
    const int wid = t >> 6;
    const int l = t & 63;
    const int lr = l & 15, lg = l >> 4;
    const int pair = blockIdx.x * 4 + wid;
    const int n = pair >> 4, j = pair & 15;
    const size_t base = ((size_t)n * NJ + j) * (size_t)(NI * HO);

    u16*   tile = t_l[wid];
    u16*   swh  = s_wh[wid];
    u16*   suh  = s_uh[wid];

    // ---- votes -> LDS tile via async global_load_lds (per-lane src, linear dest) ----
    {
        const uint4* srcq = (const uint4*)(votes + base);
        #pragma unroll
        for (int c = 0; c < 8; ++c){
            __builtin_amdgcn_global_load_lds(
                (glob_void*)(srcq + c * 64 + l),
                (lds_void*)(tile + c * 512),
                16, 0, 0);
        }
    }

    const float mki  = mask[(size_t)n * NI + l];
    const float atti = (mki == 0.f) ? -3.0e38f : 0.f;

    float aijr;                                    // lane i holds aij[i] (register)
    {   // softmax over i (in-wave) — overlaps the tile DMA
        float s = bijg[((size_t)n * NJ + j) * NI + l] * mki + atti;
        float mx = s;
        #pragma unroll
        for (int off = 32; off; off >>= 1) mx = fmaxf(mx, __shfl_xor(mx, off));
        float pe = __expf(s - mx);
        float sm = pe;
        #pragma unroll
        for (int off = 32; off; off >>= 1) sm += __shfl_xor(sm, off);
        aijr = pe / sm;
    }

    asm volatile("s_waitcnt vmcnt(0)" ::: "memory");   // tile DMA complete
    __builtin_amdgcn_sched_barrier(0);

    // ---- fnv fragment ONCE per pair: lane holds fnv[i=itile*16+lr][ht*16+lg*4 .. +3]
    uint2 fnvh[4][4];
    #pragma unroll
    for (int itile = 0; itile < 4; ++itile){
        const int row = itile * 16 + lr;
        const int key = row & 7;
        const u16* vr = tile + row * 64;
        f16x8 vb0 = *(const f16x8*)&vr[(lg ^ key) << 3];
        f16x8 vb1 = *(const f16x8*)&vr[((lg + 4) ^ key) << 3];
        #pragma unroll
        for (int ht = 0; ht < 4; ++ht){
            f16x8 a0 = *(const f16x8*)&fn1wf[(ht * 2 + 0) * 512 + l * 8];
            f16x8 a1 = *(const f16x8*)&fn1wf[(ht * 2 + 1) * 512 + l * 8];
            f32x4 c4 = {};
            c4 = __builtin_amdgcn_mfma_f32_16x16x32_f16(a0, vb0, c4, 0, 0, 0);
            c4 = __builtin_amdgcn_mfma_f32_16x16x32_f16(a1, vb1, c4, 0, 0, 0);
            const int h0 = ht * 16 + lg * 4;
            u32 lo = (u32)f2h(c4[0] + fn1b[h0])     | ((u32)f2h(c4[1] + fn1b[h0 + 1]) << 16);
            u32 hi = (u32)f2h(c4[2] + fn1b[h0 + 2]) | ((u32)f2h(c4[3] + fn1b[h0 + 3]) << 16);
            fnvh[itile][ht] = make_uint2(lo, hi);
        }
    }

    const int iters = itersp[0];
    float vj = 0.f;                                // lane l owns vj[h=l]
    for (int it = 0; it < iters; ++it){
        // nv[h=l] = sum_i aij[i]*votes[i][h]; aij via v_readlane (VALU pipe)
        const int gsh = (l >> 3) << 3;
        const int lo7 = l & 7;
        float ac0 = 0.f, ac1 = 0.f, ac2 = 0.f, ac3 = 0.f;
        #pragma unroll
        for (int ii = 0; ii < 16; ++ii){
            const int sw = (gsh ^ ((ii & 7) << 3)) + lo7;
            ac0 += bcast_lane(aijr, ii)      * h2f(tile[ ii       * 64 + sw]);
            ac1 += bcast_lane(aijr, ii + 16) * h2f(tile[(ii + 16) * 64 + sw]);
            ac2 += bcast_lane(aijr, ii + 32) * h2f(tile[(ii + 32) * 64 + sw]);
            ac3 += bcast_lane(aijr, ii + 48) * h2f(tile[(ii + 48) * 64 + sw]);
        }
        float nv = gelu_exact((ac0 + ac1) + (ac2 + ac3));
        if (it == 0) vj = nv;
        else {
            float dv = nv * alphaW[l];
            #pragma unroll
            for (int off = 32; off; off >>= 1) dv += __shfl_xor(dv, off);
            float alpha = sigm(dv + alphab[0]);
            vj = alpha * nv + (1.f - alpha) * vj;
        }
        if (it == iters - 1) break;

        // g = fe2(vj), w = fn2(vj) — readlane broadcast of vj, f32 weights.
        // No LDS mirror, no lgkmcnt round-trip.
        float ga = 0.f, wacc = 0.f;
        #pragma unroll 1
        for (int c = 0; c < 16; c += 4){
            #pragma unroll
            for (int cc = 0; cc < 4; ++cc){
                const int ch = c + cc;
                float4 wa = *(const float4*)&wAf[(ch * 64 + l) * 4];
                float4 wb = *(const float4*)&wBf[(ch * 64 + l) * 4];
                float v0 = bcast_lane(vj, ch * 4 + 0);
                float v1 = bcast_lane(vj, ch * 4 + 1);
                float v2 = bcast_lane(vj, ch * 4 + 2);
                float v3 = bcast_lane(vj, ch * 4 + 3);
                ga   += wa.x * v0 + wa.y * v1 + wa.z * v2 + wa.w * v3;
                wacc += wb.x * v0 + wb.y * v1 + wb.z * v2 + wb.w * v3;
            }
        }
        float g = ga + fe2b[l];
        swh[l] = f2h(wacc + fn2b[l]);     // mirror for M (covered by u phase below)

        // u = fe1W^T g — readlane broadcast of g (no sgh mirror)
        float ua = 0.f;
        #pragma unroll 1
        for (int c = 0; c < 16; c += 4){
            #pragma unroll
            for (int cc = 0; cc < 4; ++cc){
                const int ch = c + cc;
                float4 wc = *(const float4*)&wCtf[(ch * 64 + l) * 4];
                ua += wc.x * bcast_lane(g, ch * 4 + 0)
                    + wc.y * bcast_lane(g, ch * 4 + 1)
                    + wc.z * bcast_lane(g, ch * 4 + 2)
                    + wc.w * bcast_lane(g, ch * 4 + 3);
            }
        }
        suh[l] = f2h(ua);                 // mirror for E (covered by M phase below)
        float cv = fe1b[l] * g;
        #pragma unroll
        for (int off = 32; off; off >>= 1) cv += __shfl_xor(cv, off);

        // M[i] from in-register fnv fragment; result lands in lane l=i via predicate
        float Mreg = 0.f;
        uint2 wq[4];
        #pragma unroll
        for (int ht = 0; ht < 4; ++ht)
            wq[ht] = *(const uint2*)&swh[ht * 16 + lg * 4];
        #pragma unroll
        for (int itile = 0; itile < 4; ++itile){
            f16x2 macc = {(f16)0.f, (f16)0.f};
            #pragma unroll
            for (int ht = 0; ht < 4; ++ht){
                macc += habs2(bch2(fnvh[itile][ht].x) - bch2(wq[ht].x));
                macc += habs2(bch2(fnvh[itile][ht].y) - bch2(wq[ht].y));
            }
            float m = (float)macc[0] + (float)macc[1];
            m += __shfl_xor(m, 16);
            m += __shfl_xor(m, 32);
            if (lg == itile && lr == (l & 15)) Mreg = -m;   // lane l = itile*16+lr
        }

        // E[i=l] = votes[i].u + cv   (tile row reads from LDS; unroll 1)
        float e = cv;
        #pragma unroll 1
        for (int c2 = 0; c2 < 4; ++c2){
            uint4 q0 = *(const uint4*)&tile[l * 64 + (((2 * c2)     ^ (l & 7)) << 3)];
            uint4 q1 = *(const uint4*)&tile[l * 64 + (((2 * c2 + 1) ^ (l & 7)) << 3)];
            e = dot8h(q0, *(const uint4*)&suh[(2 * c2) * 8], e);
            e = dot8h(q1, *(const uint4*)&suh[(2 * c2 + 1) * 8], e);
        }
        aijr = tanhf(e) * sigm(Mreg * mki + atti);
    }

    out[((size_t)n * NJ + j) * HO + l] = vj;
}

extern "C" void kernel_launch(void* const* d_in, const int* in_sizes, int n_in,
                              void* d_out, int out_size, void* d_ws, size_t ws_size,
                              hipStream_t stream)
{
    (void)in_sizes; (void)n_in; (void)out_size; (void)ws_size;
    const float* x      = (const float*)d_in[0];
    const float* mask   = (const float*)d_in[1];
    const float* Wcap   = (const float*)d_in[2];
    const float* Bcap   = (const float*)d_in[3];
    const float* Wv     = (const float*)d_in[4];
    const float* Bv     = (const float*)d_in[5];
    const float* scoreW = (const float*)d_in[6];
    const float* scoreb = (const float*)d_in[7];
    const float* alphaW = (const float*)d_in[8];
    const float* alphab = (const float*)d_in[9];
    const float* fe1W   = (const float*)d_in[10];
    const float* fe1b   = (const float*)d_in[11];
    const float* fe2W   = (const float*)d_in[12];
    const float* fe2b   = (const float*)d_in[13];
    const float* fn1W   = (const float*)d_in[14];
    const float* fn1b   = (const float*)d_in[15];
    const float* fn2W   = (const float*)d_in[16];
    const float* fn2b   = (const float*)d_in[17];
    const int*   itersp = (const int*)d_in[18];
    float* out = (float*)d_out;

    char* ws = (char*)d_ws;
    u16*   xcb   = (u16*)ws;                      //   4,194,304 B  ([n][i][h] f16)
    u16*   vts   = (u16*)(ws + 4194304);          //  67,108,864 B
    float* bij   = (float*)(ws + 71303168);       //   2,097,152 B
    u16*   fn1wf = (u16*)(ws + 73400320);         //       8,192 B
    float* wAf   = (float*)(ws + 73408512);       //      16,384 B
    float* wBf   = (float*)(ws + 73424896);       //      16,384 B
    float* wCtf  = (float*)(ws + 73441280);       //      16,384 B  (~73.5 MB)

    k_prep_small<<<16, 256, 0, stream>>>(fn1W, fe2W, fn2W, fe1W,
                                         fn1wf, wAf, wBf, wCtf);
    k_xc        <<<512, 256, 0, stream>>>(x, Wcap, Bcap, xcb);
    k_votes     <<<dim3(64, 16), 256, 0, stream>>>(xcb, Wv, Bv, mask,
                                                   scoreW, scoreb, vts, bij);
    k_route     <<<2048, 256, 0, stream>>>(vts, bij, mask, alphaW, alphab,
                                           wAf, fe2b, wBf, fn2b, wCtf, fe1b,
                                           fn1wf, fn1b, itersp, out);
}

// Round 19
// 86.350 us; speedup vs baseline: 1.1259x; 1.1259x over previous
//
#include <hip/hip_runtime.h>
#include <hip/hip_bf16.h>

#define NN 512
#define NI 64
#define NJ 16
#define DD 256
#define HI 64
#define HO 64

typedef unsigned int  u32;
typedef unsigned short u16;

typedef _Float16 f16;
typedef __attribute__((ext_vector_type(2))) _Float16 f16x2;
typedef __attribute__((ext_vector_type(8))) _Float16 f16x8;
typedef __attribute__((ext_vector_type(4))) float f32x4;

__device__ __forceinline__ float gelu_exact(float x){
    return 0.5f * x * (1.0f + erff(x * 0.7071067811865476f));
}
__device__ __forceinline__ float sigm(float x){
    return 1.0f / (1.0f + __expf(-x));
}
__device__ __forceinline__ u16 f2h(float f){
    union { f16 h; u16 u; } c; c.h = (f16)f; return c.u;
}
__device__ __forceinline__ float h2f(u16 u){
    union { u16 u; f16 h; } c; c.u = u; return (float)c.h;
}
__device__ __forceinline__ f16x2 bch2(u32 x){
    union { u32 u; f16x2 h; } c; c.u = x; return c.h;
}
__device__ __forceinline__ f16x2 habs2(f16x2 a){
    union { f16x2 h; u32 u; } c; c.h = a; c.u &= 0x7FFF7FFFu; return c.h;
}
__device__ __forceinline__ float dot2f(u32 a, u32 b, float acc){
    return __builtin_amdgcn_fdot2(bch2(a), bch2(b), acc, false);
}
__device__ __forceinline__ float dot8h(uint4 q, uint4 v, float acc){
    acc = dot2f(q.x, v.x, acc);
    acc = dot2f(q.y, v.y, acc);
    acc = dot2f(q.z, v.z, acc);
    acc = dot2f(q.w, v.w, acc);
    return acc;
}
__device__ __forceinline__ float bcast_lane(float v, int lane){
    return __uint_as_float(__builtin_amdgcn_readlane(__float_as_uint(v), lane));
}

// ---- prep: small weights -> f16, gather-free layouts (16 blocks) ----
__global__ __launch_bounds__(256) void k_prep_small(
    const float* __restrict__ fn1W, const float* __restrict__ fe2W,
    const float* __restrict__ fn2W, const float* __restrict__ fe1W,
    u16* __restrict__ fn1wf, u16* __restrict__ wAh2,
    u16* __restrict__ wBh2, u16* __restrict__ wCth2)
{
    const int o = threadIdx.x + blockIdx.x * 256;
    {
        const int c = o >> 9, row = (o >> 3) & 63, e = o & 7;
        wAh2[o]  = f2h(fe2W[row * 64 + c * 8 + e]);
        wBh2[o]  = f2h(fn2W[row * 64 + c * 8 + e]);
        wCth2[o] = f2h(fe1W[(c * 8 + e) * 64 + row]);   // fe1W^T row
    }
    {
        const int q = o >> 9, ll = (o >> 3) & 63, e = o & 7;
        const int ht = q >> 1, hf = q & 1, lr = ll & 15, lg = ll >> 4;
        fn1wf[o] = f2h(fn1W[(ht * 16 + lr) * 64 + hf * 32 + lg * 8 + e]);
    }
}

// ---------------- Kernel A: xc = gelu(x @ Wcap + Bcap)  --  f16 MFMA ----------------
// XCD-bijective swizzle: the 8 same-i blocks (sharing the Wcap[i] panel) -> one XCD.
__global__ __launch_bounds__(256) void k_xc(const float* __restrict__ x,
    const float* __restrict__ Wcap, const float* __restrict__ Bcap,
    u16* __restrict__ xcb)
{
    __shared__ u16 wt_l[16384];        // 32 KB: WcapT [h][k] f16, granule-swizzled
    __shared__ u16 strip[4][1024];
    const int id = blockIdx.x;
    const int i  = ((id & 7) << 3) | (id >> 6);   // id%8 = i>>3 -> XCD
    const int nc = (id >> 3) & 7;
    const int n0 = nc * 64;
    const int t = threadIdx.x;
    const int w = t >> 6, l = t & 63;
    const int lr = l & 15, lg = l >> 4;

    {
        const float* wsrc = Wcap + (size_t)i * (DD * HI);
        const int h = t & 63, kg = t >> 6;
        #pragma unroll
        for (int p = 0; p < 32; ++p){
            const int k = (p * 4 + kg) * 2;
            u32 lo = f2h(wsrc[(size_t)k * HI + h]);
            u32 hi = f2h(wsrc[(size_t)(k + 1) * HI + h]);
            const int g = k >> 3;
            *(u32*)&wt_l[h * 256 + ((g ^ (h & 7)) << 3) + (k & 7)] = lo | (hi << 16);
        }
    }
    __syncthreads();

    const float* xrow = x + ((size_t)(n0 + 16 * w + lr) * NI + i) * DD;
    f32x4 acc[4] = {};
    #pragma unroll
    for (int ks = 0; ks < 8; ++ks){
        float4 f0 = *(const float4*)(xrow + ks * 32 + lg * 8);
        float4 f1 = *(const float4*)(xrow + ks * 32 + lg * 8 + 4);
        f16x8 a;
        a[0] = (f16)f0.x; a[1] = (f16)f0.y; a[2] = (f16)f0.z; a[3] = (f16)f0.w;
        a[4] = (f16)f1.x; a[5] = (f16)f1.y; a[6] = (f16)f1.z; a[7] = (f16)f1.w;
        #pragma unroll
        for (int ht = 0; ht < 4; ++ht){
            const int h = ht * 16 + lr;
            f16x8 b = *(const f16x8*)&wt_l[h * 256 + (((ks * 4 + lg) ^ (lr & 7)) << 3)];
            acc[ht] = __builtin_amdgcn_mfma_f32_16x16x32_f16(a, b, acc[ht], 0, 0, 0);
        }
    }

    u16* st = strip[w];
    #pragma unroll
    for (int ht = 0; ht < 4; ++ht){
        const int h = ht * 16 + lr, g = h >> 3;
        const float bc = Bcap[i * HI + h];
        #pragma unroll
        for (int r = 0; r < 4; ++r){
            const int m = lg * 4 + r;
            st[m * 64 + ((g ^ (m & 7)) << 3) + (h & 7)] = f2h(gelu_exact(acc[ht][r] + bc));
        }
    }
    {
        const int row = l >> 2, g0 = (l & 3) * 2;
        const size_t off = ((size_t)(n0 + 16 * w + row) * NI + i) * HI;
        #pragma unroll
        for (int gg = g0; gg < g0 + 2; ++gg){
            uint4 q = *(const uint4*)&st[row * 64 + ((gg ^ (row & 7)) << 3)];
            *(uint4*)(xcb + off + gg * 8) = q;
        }
    }
}

// ------- Kernel B: one block per (i,j); votes (f16 MFMA) + bij.  NO fnv. -------
__global__ __launch_bounds__(256) void k_votes(
    const u16* __restrict__ xcb, const float* __restrict__ Wv,
    const float* __restrict__ Bv, const float* __restrict__ mask,
    const float* __restrict__ scoreW, const float* __restrict__ scoreb,
    u16* __restrict__ votes, float* __restrict__ bij)
{
    __shared__ u16 vstrip[4][1024];
    const int i = blockIdx.x, j = blockIdx.y;
    const int t = threadIdx.x, w = t >> 6, l = t & 63;
    const int lr = l & 15, lg = l >> 4;
    const int isw = i & 7;

    f16x8 wb0[4], wb1[4];
    const float* wvp = Wv + (size_t)(i * NJ + j) * 4096;
    float bv[4], swv[4];
    #pragma unroll
    for (int ht = 0; ht < 4; ++ht){
        const int h = ht * 16 + lr;
        #pragma unroll
        for (int e = 0; e < 8; ++e){
            wb0[ht][e] = (f16)wvp[(lg * 8 + e) * 64 + h];
            wb1[ht][e] = (f16)wvp[(32 + lg * 8 + e) * 64 + h];
        }
        bv[ht]  = Bv[(size_t)(i * NJ + j) * HO + h];
        swv[ht] = scoreW[h];
    }
    const float sb = scoreb[0];
    u16* vst = vstrip[w];

    for (int nc = 0; nc < 8; ++nc){
        const int n0 = nc * 64 + 16 * w;
        const u16* ar = xcb + ((size_t)(n0 + lr) * NI + i) * HI + lg * 8;
        f16x8 a0 = *(const f16x8*)ar;
        f16x8 a1 = *(const f16x8*)(ar + 32);
        float mk[4];
        #pragma unroll
        for (int r = 0; r < 4; ++r)
            mk[r] = mask[(size_t)(n0 + lg * 4 + r) * NI + i];

        float p[4] = {};
        #pragma unroll
        for (int ht = 0; ht < 4; ++ht){
            f32x4 c4 = {};
            c4 = __builtin_amdgcn_mfma_f32_16x16x32_f16(a0, wb0[ht], c4, 0, 0, 0);
            c4 = __builtin_amdgcn_mfma_f32_16x16x32_f16(a1, wb1[ht], c4, 0, 0, 0);
            const int h = ht * 16 + lr, gp = h >> 3;
            #pragma unroll
            for (int r = 0; r < 4; ++r){
                const int rs = lg * 4 + r;
                float val = (c4[r] + bv[ht]) * mk[r];
                p[r] += val * swv[ht];
                vst[rs * 64 + ((gp ^ (rs & 7)) << 3) + (h & 7)] = f2h(val);
            }
        }
        #pragma unroll
        for (int r = 0; r < 4; ++r){
            float s = p[r];
            s += __shfl_xor(s, 1); s += __shfl_xor(s, 2);
            s += __shfl_xor(s, 4); s += __shfl_xor(s, 8);
            if (lr == 0)
                bij[((size_t)(n0 + lg * 4 + r) * NJ + j) * NI + i] = s + sb;
        }

        {
            const int row = l >> 2, g0 = (l & 3) * 2;
            const size_t off = (((size_t)(nc * 64 + 16 * w + row) * NJ + j) * NI + i) * HO;
            #pragma unroll
            for (int gg = g0; gg < g0 + 2; ++gg){
                uint4 qv = *(const uint4*)&vst[row * 64 + ((gg ^ (row & 7)) << 3)];
                *(uint4*)(votes + off + ((gg ^ isw) << 3)) = qv;
            }
        }
    }
}

// ---------------- Kernel C: routing; ONE wave per (n,j), ZERO barriers ----------------
// r16 body exactly (best measured: 46.0 us, VGPR 116): reg staging in two
// 4-deep batches, fdot2 with f16 LDS mirrors, aij via v_readlane, fnvh
// fragment once per pair, unroll-1 dot phases. No cap attributes.
__global__ __launch_bounds__(256) void k_route(
    const u16* __restrict__ votes, const float* __restrict__ bijg,
    const float* __restrict__ mask,
    const float* __restrict__ alphaW, const float* __restrict__ alphab,
    const u16* __restrict__ wAh2, const float* __restrict__ fe2b,
    const u16* __restrict__ wBh2, const float* __restrict__ fn2b,
    const u16* __restrict__ wCth2, const float* __restrict__ fe1b,
    const u16* __restrict__ fn1wf, const float* __restrict__ fn1b,
    const int* __restrict__ itersp, float* __restrict__ out)
{
    __shared__ u16 t_l[4][4096];                       // 8 KB votes tile per wave
    __shared__ float s_M[4][64];
    __shared__ alignas(16) u16 s_vjh[4][64];           // f16 mirrors for dot2
    __shared__ alignas(16) u16 s_gh[4][64];
    __shared__ alignas(16) u16 s_wh[4][64];
    __shared__ alignas(16) u16 s_uh[4][64];

    const int t = threadIdx.x;
    const int wid = t >> 6;
    const int l = t & 63;
    const int lr = l & 15, lg = l >> 4;
    const int pair = blockIdx.x * 4 + wid;
    const int n = pair >> 4, j = pair & 15;
    const size_t base = ((size_t)n * NJ + j) * (size_t)(NI * HO);

    u16*   tile = t_l[wid];
    float* Mw   = s_M[wid];
    u16*   vjh  = s_vjh[wid];
    u16*   sgh  = s_gh[wid];
    u16*   swh  = s_wh[wid];
    u16*   suh  = s_uh[wid];

    // ---- votes -> LDS tile: two 4-deep batches (16 regs in flight) ----
    {
        const uint4* src = (const uint4*)(votes + base);
        #pragma unroll
        for (int half = 0; half < 2; ++half){
            uint4 tb[4];
            #pragma unroll
            for (int c = 0; c < 4; ++c) tb[c] = src[(half * 4 + c) * 64 + l];
            #pragma unroll
            for (int c = 0; c < 4; ++c)
                *(uint4*)&tile[((half * 4 + c) * 64 + l) * 8] = tb[c];
        }
    }

    const float mki  = mask[(size_t)n * NI + l];
    const float atti = (mki == 0.f) ? -3.0e38f : 0.f;

    float aijr;                                    // lane i holds aij[i] (register)
    {   // softmax over i (in-wave)
        float s = bijg[((size_t)n * NJ + j) * NI + l] * mki + atti;
        float mx = s;
        #pragma unroll
        for (int off = 32; off; off >>= 1) mx = fmaxf(mx, __shfl_xor(mx, off));
        float pe = __expf(s - mx);
        float sm = pe;
        #pragma unroll
        for (int off = 32; off; off >>= 1) sm += __shfl_xor(sm, off);
        aijr = pe / sm;
    }

    // ---- fnv fragment ONCE per pair: lane holds fnv[i=itile*16+lr][ht*16+lg*4 .. +3]
    uint2 fnvh[4][4];
    #pragma unroll
    for (int itile = 0; itile < 4; ++itile){
        const int row = itile * 16 + lr;
        const int key = row & 7;
        const u16* vr = tile + row * 64;
        f16x8 vb0 = *(const f16x8*)&vr[(lg ^ key) << 3];
        f16x8 vb1 = *(const f16x8*)&vr[((lg + 4) ^ key) << 3];
        #pragma unroll
        for (int ht = 0; ht < 4; ++ht){
            f16x8 a0 = *(const f16x8*)&fn1wf[(ht * 2 + 0) * 512 + l * 8];
            f16x8 a1 = *(const f16x8*)&fn1wf[(ht * 2 + 1) * 512 + l * 8];
            f32x4 c4 = {};
            c4 = __builtin_amdgcn_mfma_f32_16x16x32_f16(a0, vb0, c4, 0, 0, 0);
            c4 = __builtin_amdgcn_mfma_f32_16x16x32_f16(a1, vb1, c4, 0, 0, 0);
            const int h0 = ht * 16 + lg * 4;
            u32 lo = (u32)f2h(c4[0] + fn1b[h0])     | ((u32)f2h(c4[1] + fn1b[h0 + 1]) << 16);
            u32 hi = (u32)f2h(c4[2] + fn1b[h0 + 2]) | ((u32)f2h(c4[3] + fn1b[h0 + 3]) << 16);
            fnvh[itile][ht] = make_uint2(lo, hi);
        }
    }

    const int iters = itersp[0];
    float vj = 0.f;                                // lane l owns vj[h=l]
    for (int it = 0; it < iters; ++it){
        // nv[h=l] = sum_i aij[i]*votes[i][h]; aij via v_readlane (VALU pipe)
        const int gsh = (l >> 3) << 3;
        const int lo7 = l & 7;
        float ac0 = 0.f, ac1 = 0.f, ac2 = 0.f, ac3 = 0.f;
        #pragma unroll
        for (int ii = 0; ii < 16; ++ii){
            const int sw = (gsh ^ ((ii & 7) << 3)) + lo7;
            ac0 += bcast_lane(aijr, ii)      * h2f(tile[ ii       * 64 + sw]);
            ac1 += bcast_lane(aijr, ii + 16) * h2f(tile[(ii + 16) * 64 + sw]);
            ac2 += bcast_lane(aijr, ii + 32) * h2f(tile[(ii + 32) * 64 + sw]);
            ac3 += bcast_lane(aijr, ii + 48) * h2f(tile[(ii + 48) * 64 + sw]);
        }
        float nv = gelu_exact((ac0 + ac1) + (ac2 + ac3));
        if (it == 0) vj = nv;
        else {
            float dv = nv * alphaW[l];
            #pragma unroll
            for (int off = 32; off; off >>= 1) dv += __shfl_xor(dv, off);
            float alpha = sigm(dv + alphab[0]);
            vj = alpha * nv + (1.f - alpha) * vj;
        }
        if (it == iters - 1) break;
        vjh[l] = f2h(vj);

        // g = fe2(vj), w = fn2(vj)   (unroll 1: bounded loads in flight)
        float ga = 0.f, wacc = 0.f;
        #pragma unroll 1
        for (int c2 = 0; c2 < 4; ++c2){
            uint4 vq0 = *(const uint4*)&vjh[(2 * c2) * 8];
            uint4 vq1 = *(const uint4*)&vjh[(2 * c2 + 1) * 8];
            uint4 wa0 = *(const uint4*)&wAh2[((2 * c2) * 64 + l) * 8];
            uint4 wa1 = *(const uint4*)&wAh2[((2 * c2 + 1) * 64 + l) * 8];
            uint4 wb0 = *(const uint4*)&wBh2[((2 * c2) * 64 + l) * 8];
            uint4 wb1 = *(const uint4*)&wBh2[((2 * c2 + 1) * 64 + l) * 8];
            ga   = dot8h(wa0, vq0, ga);
            ga   = dot8h(wa1, vq1, ga);
            wacc = dot8h(wb0, vq0, wacc);
            wacc = dot8h(wb1, vq1, wacc);
        }
        float g = ga + fe2b[l];
        sgh[l] = f2h(g);
        swh[l] = f2h(wacc + fn2b[l]);

        // u = fe1W^T g ; cv = fe1b . g   (unroll 1)
        float ua = 0.f;
        #pragma unroll 1
        for (int c2 = 0; c2 < 4; ++c2){
            uint4 gq0 = *(const uint4*)&sgh[(2 * c2) * 8];
            uint4 gq1 = *(const uint4*)&sgh[(2 * c2 + 1) * 8];
            uint4 wc0 = *(const uint4*)&wCth2[((2 * c2) * 64 + l) * 8];
            uint4 wc1 = *(const uint4*)&wCth2[((2 * c2 + 1) * 64 + l) * 8];
            ua = dot8h(wc0, gq0, ua);
            ua = dot8h(wc1, gq1, ua);
        }
        suh[l] = f2h(ua);
        float cv = fe1b[l] * g;
        #pragma unroll
        for (int off = 32; off; off >>= 1) cv += __shfl_xor(cv, off);

        // M[i] from in-register fnv fragment (packed f16), reduce over lg
        uint2 wq[4];
        #pragma unroll
        for (int ht = 0; ht < 4; ++ht)
            wq[ht] = *(const uint2*)&swh[ht * 16 + lg * 4];
        #pragma unroll
        for (int itile = 0; itile < 4; ++itile){
            f16x2 macc = {(f16)0.f, (f16)0.f};
            #pragma unroll
            for (int ht = 0; ht < 4; ++ht){
                macc += habs2(bch2(fnvh[itile][ht].x) - bch2(wq[ht].x));
                macc += habs2(bch2(fnvh[itile][ht].y) - bch2(wq[ht].y));
            }
            float m = (float)macc[0] + (float)macc[1];
            m += __shfl_xor(m, 16);
            m += __shfl_xor(m, 32);
            if (l < 16) Mw[itile * 16 + l] = -m;
        }

        // E[i=l] = votes[i].u + cv   (tile row reads from LDS; unroll 1)
        float e = cv;
        #pragma unroll 1
        for (int c2 = 0; c2 < 4; ++c2){
            uint4 q0 = *(const uint4*)&tile[l * 64 + (((2 * c2)     ^ (l & 7)) << 3)];
            uint4 q1 = *(const uint4*)&tile[l * 64 + (((2 * c2 + 1) ^ (l & 7)) << 3)];
            e = dot8h(q0, *(const uint4*)&suh[(2 * c2) * 8], e);
            e = dot8h(q1, *(const uint4*)&suh[(2 * c2 + 1) * 8], e);
        }
        aijr = tanhf(e) * sigm(Mw[l] * mki + atti);
    }

    out[((size_t)n * NJ + j) * HO + l] = vj;
}

extern "C" void kernel_launch(void* const* d_in, const int* in_sizes, int n_in,
                              void* d_out, int out_size, void* d_ws, size_t ws_size,
                              hipStream_t stream)
{
    (void)in_sizes; (void)n_in; (void)out_size; (void)ws_size;
    const float* x      = (const float*)d_in[0];
    const float* mask   = (const float*)d_in[1];
    const float* Wcap   = (const float*)d_in[2];
    const float* Bcap   = (const float*)d_in[3];
    const float* Wv     = (const float*)d_in[4];
    const float* Bv     = (const float*)d_in[5];
    const float* scoreW = (const float*)d_in[6];
    const float* scoreb = (const float*)d_in[7];
    const float* alphaW = (const float*)d_in[8];
    const float* alphab = (const float*)d_in[9];
    const float* fe1W   = (const float*)d_in[10];
    const float* fe1b   = (const float*)d_in[11];
    const float* fe2W   = (const float*)d_in[12];
    const float* fe2b   = (const float*)d_in[13];
    const float* fn1W   = (const float*)d_in[14];
    const float* fn1b   = (const float*)d_in[15];
    const float* fn2W   = (const float*)d_in[16];
    const float* fn2b   = (const float*)d_in[17];
    const int*   itersp = (const int*)d_in[18];
    float* out = (float*)d_out;

    char* ws = (char*)d_ws;
    u16*   xcb   = (u16*)ws;                      //   4,194,304 B  ([n][i][h] f16)
    u16*   vts   = (u16*)(ws + 4194304);          //  67,108,864 B
    float* bij   = (float*)(ws + 71303168);       //   2,097,152 B
    u16*   fn1wf = (u16*)(ws + 73400320);         //       8,192 B
    u16*   wAh2  = (u16*)(ws + 73408512);         //       8,192 B
    u16*   wBh2  = (u16*)(ws + 73416704);         //       8,192 B
    u16*   wCth2 = (u16*)(ws + 73424896);         //       8,192 B  (~73.4 MB)

    k_prep_small<<<16, 256, 0, stream>>>(fn1W, fe2W, fn2W, fe1W,
                                         fn1wf, wAh2, wBh2, wCth2);
    k_xc        <<<512, 256, 0, stream>>>(x, Wcap, Bcap, xcb);
    k_votes     <<<dim3(64, 16), 256, 0, stream>>>(xcb, Wv, Bv, mask,
                                                   scoreW, scoreb, vts, bij);
    k_route     <<<2048, 256, 0, stream>>>(vts, bij, mask, alphaW, alphab,
                                           wAh2, fe2b, wBh2, fn2b, wCth2, fe1b,
                                           fn1wf, fn1b, itersp, out);
}